// Round 22
// baseline (31.492 us; speedup 1.0000x reference)
//
#include <hip/hip_runtime.h>
#include <hip/hip_bf16.h>

#define N_LATENT 64
#define N_OUT    64
#define CAP      256   // rows/sample capacity: mean 65.5, sd ~8 -> 23 sigma
#define CSTRIDE  32    // cursor padded to 128 B (CDNA L2 line) per sample.
                       // Round-21: 64-B padding (CSTRIDE=16) won 10.5 us vs
                       // unpadded; 128-B removes the last 2-samples/line
                       // false sharing.

typedef __attribute__((ext_vector_type(8))) _Float16 f16x8;
typedef __attribute__((ext_vector_type(4))) float    f32x4;

union U4H8 { uint4 u4; f16x8 h8; };

// ---- Kernel A: ONE pass over sid builds per-sample row lists ----
__global__ void build_lists_kernel(const int* __restrict__ sid,
                                   int* __restrict__ cursor,
                                   int* __restrict__ list,
                                   int n4)
{
    const int i = blockIdx.x * blockDim.x + threadIdx.x;
    if (i < n4) {
        const int4 v = ((const int4*)sid)[i];
        int p;
        p = atomicAdd(&cursor[v.x * CSTRIDE], 1); if (p < CAP) list[v.x * CAP + p] = 4 * i;
        p = atomicAdd(&cursor[v.y * CSTRIDE], 1); if (p < CAP) list[v.y * CAP + p] = 4 * i + 1;
        p = atomicAdd(&cursor[v.z * CSTRIDE], 1); if (p < CAP) list[v.z * CAP + p] = 4 * i + 2;
        p = atomicAdd(&cursor[v.w * CSTRIDE], 1); if (p < CAP) list[v.w * CAP + p] = 4 * i + 3;
    }
}

// ---- Kernel B: TWO blocks per sample (round-17 split, retested now that
// the 10us build overhead is gone): block b -> sample b>>1, half=b&1; wave w
// covers tile 2w+half (stride 8) -> the sample's 8 wave-slots cover tiles
// 0..7 exactly once; avg 5 tiles => every wave <=1 tile (kills the serial
// 2-tile tail of the 1-block version). B-frags of A[s] (f16) staged to LDS
// per block. k-map identical for A/B fragments; C/D map col=lane&15,
// row=(lane>>4)*4+r. fp32 residual via u re-read. absmax 0.25 (f16 inputs).
__global__ __launch_bounds__(256) void decoder_mfma_kernel(
    const float* __restrict__ u,
    const float* __restrict__ amat,
    const float* __restrict__ offsets,
    const int*   __restrict__ cursor,
    const int*   __restrict__ list,
    float*       __restrict__ out)
{
    __shared__ uint Bf[8 * 64 * 4];            // (kk*4+nt, lane) -> 4 dwords

    const int s    = blockIdx.x >> 1;
    const int half = blockIdx.x & 1;
    const int tid  = threadIdx.x;
    const int lane = tid & 63;
    const int wave = tid >> 6;                 // 0..3

    int n = cursor[s * CSTRIDE];
    n = (n < CAP) ? n : CAP;
    if (n == 0) return;                        // uniform exit, before barrier
    const int tiles = (n + 15) >> 4;
    if (half == 1 && tiles <= 1) return;       // second block unneeded

    const float* __restrict__ Ag  = amat + (size_t)s * (N_LATENT * N_OUT);
    const int*   __restrict__ lst = list + s * CAP;

    // stage B fragments: combo c = kk*4+nt; wave w stages {w, w+4}
    for (int c = wave; c < 8; c += 4) {
        const int kk  = c >> 2;
        const int nt  = c & 3;
        const int kb  = kk * 32 + (lane >> 4) * 8;   // 8 contiguous k
        const int col = nt * 16 + (lane & 15);
        U4H8 x;
#pragma unroll
        for (int j = 0; j < 8; ++j)
            x.h8[j] = (_Float16)Ag[(kb + j) * N_OUT + col];
        *((uint4*)&Bf[(c * 64 + lane) * 4]) = x.u4;
    }
    __syncthreads();

    float off_nt[4];
#pragma unroll
    for (int nt = 0; nt < 4; ++nt)
        off_nt[nt] = offsets[(size_t)s * N_OUT + nt * 16 + (lane & 15)];

    for (int t = 2 * wave + half; t < tiles; t += 8) {
        // A fragment: 16 rows (lane&15), k-chunk (lane>>4)*8
        const int ridx = t * 16 + (lane & 15);
        const int brow = lst[(ridx < n) ? ridx : 0];      // pad: row list[0]
        const float* __restrict__ up =
            u + (size_t)brow * N_LATENT + ((lane >> 4) * 8);
        f16x8 a0, a1;
        {
            const float4 p0 = *(const float4*)(up);
            const float4 p1 = *(const float4*)(up + 4);
            const float4 p2 = *(const float4*)(up + 32);  // kk=1: k += 32
            const float4 p3 = *(const float4*)(up + 36);
            a0[0] = (_Float16)p0.x; a0[1] = (_Float16)p0.y;
            a0[2] = (_Float16)p0.z; a0[3] = (_Float16)p0.w;
            a0[4] = (_Float16)p1.x; a0[5] = (_Float16)p1.y;
            a0[6] = (_Float16)p1.z; a0[7] = (_Float16)p1.w;
            a1[0] = (_Float16)p2.x; a1[1] = (_Float16)p2.y;
            a1[2] = (_Float16)p2.z; a1[3] = (_Float16)p2.w;
            a1[4] = (_Float16)p3.x; a1[5] = (_Float16)p3.y;
            a1[6] = (_Float16)p3.z; a1[7] = (_Float16)p3.w;
        }

        // epilogue row indices (C map: row=(lane>>4)*4+r)
        int  b2[4]; bool val[4];
#pragma unroll
        for (int r = 0; r < 4; ++r) {
            const int ridx2 = t * 16 + (lane >> 4) * 4 + r;
            val[r] = (ridx2 < n);
            b2[r]  = lst[val[r] ? ridx2 : 0];
        }

#pragma unroll
        for (int nt = 0; nt < 4; ++nt) {
            U4H8 b0, b1;
            b0.u4 = *((const uint4*)&Bf[((0 * 4 + nt) * 64 + lane) * 4]);
            b1.u4 = *((const uint4*)&Bf[((1 * 4 + nt) * 64 + lane) * 4]);
            f32x4 acc = {0.f, 0.f, 0.f, 0.f};
            acc = __builtin_amdgcn_mfma_f32_16x16x32_f16(a0, b0.h8, acc, 0, 0, 0);
            acc = __builtin_amdgcn_mfma_f32_16x16x32_f16(a1, b1.h8, acc, 0, 0, 0);

            const int col = nt * 16 + (lane & 15);
#pragma unroll
            for (int r = 0; r < 4; ++r) {
                if (val[r]) {
                    const size_t idx = (size_t)b2[r] * N_OUT + col;
                    out[idx] = u[idx] + acc[r] + off_nt[nt];
                }
            }
        }
    }
}

extern "C" void kernel_launch(void* const* d_in, const int* in_sizes, int n_in,
                              void* d_out, int out_size, void* d_ws, size_t ws_size,
                              hipStream_t stream)
{
    const float* u       = (const float*)d_in[0];
    const int*   sid     = (const int*)d_in[1];
    const float* amat    = (const float*)d_in[2];
    const float* offsets = (const float*)d_in[3];
    float*       out     = (float*)d_out;

    const int batch    = in_sizes[0] / N_LATENT;            // 65536
    const int n_sample = in_sizes[2] / (N_LATENT * N_OUT);  // 1000

    // ws layout (ints): [0, n_sample*CSTRIDE) padded cursors
    //                   | [n_sample*CSTRIDE, +n_sample*CAP) lists
    int* cursor = (int*)d_ws;
    int* list   = cursor + (size_t)n_sample * CSTRIDE;

    hipMemsetAsync(cursor, 0, (size_t)n_sample * CSTRIDE * sizeof(int), stream);

    const int n4 = batch / 4;
    build_lists_kernel<<<(n4 + 255) / 256, 256, 0, stream>>>(
        sid, cursor, list, n4);

    decoder_mfma_kernel<<<n_sample * 2, 256, 0, stream>>>(
        u, amat, offsets, cursor, list, out);
}

// Round 23
// 29.344 us; speedup vs baseline: 1.0732x; 1.0732x over previous
//
#include <hip/hip_runtime.h>
#include <hip/hip_bf16.h>

#define N_LATENT 64
#define N_OUT    64
#define CAP      256   // rows/sample capacity: mean 65.5, sd ~8 -> 23 sigma
#define CSTRIDE  16    // cursor padded to 64 B/sample (round-21: won 10.5 us
                       // vs unpadded; round-22's 128-B variant was neutral)
#define NWAVES   5     // 320-thr blocks: tiles=ceil(n/16)=5 typical -> 1:1
                       // wave:tile map kills the {2,1,1,1} serial tail of the
                       // 4-wave block WITHOUT duplicating A staging (the
                       // round-22 2-block split's regression).

typedef __attribute__((ext_vector_type(8))) _Float16 f16x8;
typedef __attribute__((ext_vector_type(4))) float    f32x4;

union U4H8 { uint4 u4; f16x8 h8; };

// ---- Kernel A: ONE pass over sid builds per-sample row lists ----
__global__ void build_lists_kernel(const int* __restrict__ sid,
                                   int* __restrict__ cursor,
                                   int* __restrict__ list,
                                   int n4)
{
    const int i = blockIdx.x * blockDim.x + threadIdx.x;
    if (i < n4) {
        const int4 v = ((const int4*)sid)[i];
        int p;
        p = atomicAdd(&cursor[v.x * CSTRIDE], 1); if (p < CAP) list[v.x * CAP + p] = 4 * i;
        p = atomicAdd(&cursor[v.y * CSTRIDE], 1); if (p < CAP) list[v.y * CAP + p] = 4 * i + 1;
        p = atomicAdd(&cursor[v.z * CSTRIDE], 1); if (p < CAP) list[v.z * CAP + p] = 4 * i + 2;
        p = atomicAdd(&cursor[v.w * CSTRIDE], 1); if (p < CAP) list[v.w * CAP + p] = 4 * i + 3;
    }
}

// ---- Kernel B: one block (320 thr = 5 waves) per sample; MFMA compute ----
// Round-21 champion structure; only change: 5 waves so wave w owns tile w
// (stride 5) -> typical 5-tile sample has no serial tile chain. B-frags of
// A[s] (f16) staged once to LDS (8 KB). Per 16-row tile: 8 MFMA (4 n-tiles
// x 2 k-halves of 16x16x32). k-map identical for A/B fragments; C/D map
// col=lane&15, row=(lane>>4)*4+r. fp32 residual via u re-read in epilogue.
__global__ __launch_bounds__(64 * NWAVES) void decoder_mfma_kernel(
    const float* __restrict__ u,
    const float* __restrict__ amat,
    const float* __restrict__ offsets,
    const int*   __restrict__ cursor,
    const int*   __restrict__ list,
    float*       __restrict__ out)
{
    __shared__ uint Bf[8 * 64 * 4];            // (kk*4+nt, lane) -> 4 dwords

    const int s    = blockIdx.x;
    const int tid  = threadIdx.x;
    const int lane = tid & 63;
    const int wave = tid >> 6;                 // 0..4

    int n = cursor[s * CSTRIDE];
    n = (n < CAP) ? n : CAP;
    if (n == 0) return;                        // uniform exit, before barrier

    const float* __restrict__ Ag  = amat + (size_t)s * (N_LATENT * N_OUT);
    const int*   __restrict__ lst = list + s * CAP;

    // stage B fragments: combo c = kk*4+nt over 5 waves
    for (int c = wave; c < 8; c += NWAVES) {
        const int kk  = c >> 2;
        const int nt  = c & 3;
        const int kb  = kk * 32 + (lane >> 4) * 8;   // 8 contiguous k
        const int col = nt * 16 + (lane & 15);
        U4H8 x;
#pragma unroll
        for (int j = 0; j < 8; ++j)
            x.h8[j] = (_Float16)Ag[(kb + j) * N_OUT + col];
        *((uint4*)&Bf[(c * 64 + lane) * 4]) = x.u4;
    }
    __syncthreads();

    const int tiles = (n + 15) >> 4;

    float off_nt[4];
#pragma unroll
    for (int nt = 0; nt < 4; ++nt)
        off_nt[nt] = offsets[(size_t)s * N_OUT + nt * 16 + (lane & 15)];

    for (int t = wave; t < tiles; t += NWAVES) {
        // A fragment: 16 rows (lane&15), k-chunk (lane>>4)*8
        const int ridx = t * 16 + (lane & 15);
        const int brow = lst[(ridx < n) ? ridx : 0];      // pad: row list[0]
        const float* __restrict__ up =
            u + (size_t)brow * N_LATENT + ((lane >> 4) * 8);
        f16x8 a0, a1;
        {
            const float4 p0 = *(const float4*)(up);
            const float4 p1 = *(const float4*)(up + 4);
            const float4 p2 = *(const float4*)(up + 32);  // kk=1: k += 32
            const float4 p3 = *(const float4*)(up + 36);
            a0[0] = (_Float16)p0.x; a0[1] = (_Float16)p0.y;
            a0[2] = (_Float16)p0.z; a0[3] = (_Float16)p0.w;
            a0[4] = (_Float16)p1.x; a0[5] = (_Float16)p1.y;
            a0[6] = (_Float16)p1.z; a0[7] = (_Float16)p1.w;
            a1[0] = (_Float16)p2.x; a1[1] = (_Float16)p2.y;
            a1[2] = (_Float16)p2.z; a1[3] = (_Float16)p2.w;
            a1[4] = (_Float16)p3.x; a1[5] = (_Float16)p3.y;
            a1[6] = (_Float16)p3.z; a1[7] = (_Float16)p3.w;
        }

        // epilogue row indices (C map: row=(lane>>4)*4+r)
        int  b2[4]; bool val[4];
#pragma unroll
        for (int r = 0; r < 4; ++r) {
            const int ridx2 = t * 16 + (lane >> 4) * 4 + r;
            val[r] = (ridx2 < n);
            b2[r]  = lst[val[r] ? ridx2 : 0];
        }

#pragma unroll
        for (int nt = 0; nt < 4; ++nt) {
            U4H8 b0, b1;
            b0.u4 = *((const uint4*)&Bf[((0 * 4 + nt) * 64 + lane) * 4]);
            b1.u4 = *((const uint4*)&Bf[((1 * 4 + nt) * 64 + lane) * 4]);
            f32x4 acc = {0.f, 0.f, 0.f, 0.f};
            acc = __builtin_amdgcn_mfma_f32_16x16x32_f16(a0, b0.h8, acc, 0, 0, 0);
            acc = __builtin_amdgcn_mfma_f32_16x16x32_f16(a1, b1.h8, acc, 0, 0, 0);

            const int col = nt * 16 + (lane & 15);
#pragma unroll
            for (int r = 0; r < 4; ++r) {
                if (val[r]) {
                    const size_t idx = (size_t)b2[r] * N_OUT + col;
                    out[idx] = u[idx] + acc[r] + off_nt[nt];
                }
            }
        }
    }
}

extern "C" void kernel_launch(void* const* d_in, const int* in_sizes, int n_in,
                              void* d_out, int out_size, void* d_ws, size_t ws_size,
                              hipStream_t stream)
{
    const float* u       = (const float*)d_in[0];
    const int*   sid     = (const int*)d_in[1];
    const float* amat    = (const float*)d_in[2];
    const float* offsets = (const float*)d_in[3];
    float*       out     = (float*)d_out;

    const int batch    = in_sizes[0] / N_LATENT;            // 65536
    const int n_sample = in_sizes[2] / (N_LATENT * N_OUT);  // 1000

    // ws layout (ints): [0, n_sample*CSTRIDE) padded cursors
    //                   | [n_sample*CSTRIDE, +n_sample*CAP) lists
    int* cursor = (int*)d_ws;
    int* list   = cursor + (size_t)n_sample * CSTRIDE;

    hipMemsetAsync(cursor, 0, (size_t)n_sample * CSTRIDE * sizeof(int), stream);

    const int n4 = batch / 4;
    build_lists_kernel<<<(n4 + 255) / 256, 256, 0, stream>>>(
        sid, cursor, list, n4);

    decoder_mfma_kernel<<<n_sample, 64 * NWAVES, 0, stream>>>(
        u, amat, offsets, cursor, list, out);
}

// Round 26
// 25.447 us; speedup vs baseline: 1.2376x; 1.1532x over previous
//
#include <hip/hip_runtime.h>
#include <hip/hip_bf16.h>

#define N_LATENT 64
#define N_OUT    64
#define CAP      256   // rows/sample capacity: mean 65.5, sd ~8 -> 23 sigma
#define CSTRIDE  16    // cursor padded to 64 B/sample (round-21: -10.5 us)
#define NWAVES   5     // 1:1 wave:tile for the typical 5-tile sample (r23)
#define TPAD     68    // LDS tile row pitch (floats): 16B-aligned, bank-spread

typedef __attribute__((ext_vector_type(8))) _Float16 f16x8;
typedef __attribute__((ext_vector_type(4))) float    f32x4;

union U4H8 { uint4 u4; f16x8 h8; };

// ---- Kernel A: ONE pass over sid builds per-sample row lists ----
// 1 row/thread (256 blocks) instead of int4/thread (64 blocks): same atomic
// count, 4x the TLP to hide the device-scope atomic latency.
__global__ __launch_bounds__(256) void build_lists_kernel(
    const int* __restrict__ sid,
    int* __restrict__ cursor,
    int* __restrict__ list,
    int batch)
{
    const int i = blockIdx.x * blockDim.x + threadIdx.x;
    if (i < batch) {
        const int s = sid[i];
        const int p = atomicAdd(&cursor[s * CSTRIDE], 1);
        if (p < CAP) list[s * CAP + p] = i;
    }
}

// ---- Kernel B: one block (320 thr = 5 waves) per sample; MFMA compute ----
// Round-23 structure. Change: epilogue via per-wave LDS transpose tile.
// MFMA acc (scattered (row,col) per lane) -> LDS [16][TPAD] -> ONE coalesced
// pass of float4 {u-read, add, out-write} per 4 rows. 8 vector VMEM ops/lane
// /tile vs 32 scalar before. Math order (u+acc)+off unchanged -> bitwise
// identical output (absmax 0.25). Per-wave LDS region: no cross-wave barrier.
__global__ __launch_bounds__(64 * NWAVES) void decoder_mfma_kernel(
    const float* __restrict__ u,
    const float* __restrict__ amat,
    const float* __restrict__ offsets,
    const int*   __restrict__ cursor,
    const int*   __restrict__ list,
    float*       __restrict__ out)
{
    __shared__ uint  Bf[8 * 64 * 4];           // B fragments: 8 KB
    __shared__ float Ot[NWAVES][16 * TPAD];    // per-wave acc tiles: 21.25 KB

    const int s    = blockIdx.x;
    const int tid  = threadIdx.x;
    const int lane = tid & 63;
    const int wave = tid >> 6;                 // 0..4

    int n = cursor[s * CSTRIDE];
    n = (n < CAP) ? n : CAP;
    if (n == 0) return;                        // uniform exit, before barrier

    const float* __restrict__ Ag  = amat + (size_t)s * (N_LATENT * N_OUT);
    const int*   __restrict__ lst = list + s * CAP;

    // stage B fragments: combo c = kk*4+nt over 5 waves
    for (int c = wave; c < 8; c += NWAVES) {
        const int kk  = c >> 2;
        const int nt  = c & 3;
        const int kb  = kk * 32 + (lane >> 4) * 8;   // 8 contiguous k
        const int col = nt * 16 + (lane & 15);
        U4H8 x;
#pragma unroll
        for (int j = 0; j < 8; ++j)
            x.h8[j] = (_Float16)Ag[(kb + j) * N_OUT + col];
        *((uint4*)&Bf[(c * 64 + lane) * 4]) = x.u4;
    }
    __syncthreads();

    const int tiles = (n + 15) >> 4;

    // epilogue per-lane offsets: cols (lane&15)*4 .. +3
    const float4 offv = *(const float4*)(offsets + (size_t)s * N_OUT + (lane & 15) * 4);

    float* __restrict__ myT = &Ot[wave][0];

    for (int t = wave; t < tiles; t += NWAVES) {
        // A fragment: 16 rows (lane&15), k-chunk (lane>>4)*8
        const int ridx = t * 16 + (lane & 15);
        const int brow = lst[(ridx < n) ? ridx : 0];      // pad: row list[0]
        const float* __restrict__ up =
            u + (size_t)brow * N_LATENT + ((lane >> 4) * 8);
        f16x8 a0, a1;
        {
            const float4 p0 = *(const float4*)(up);
            const float4 p1 = *(const float4*)(up + 4);
            const float4 p2 = *(const float4*)(up + 32);  // kk=1: k += 32
            const float4 p3 = *(const float4*)(up + 36);
            a0[0] = (_Float16)p0.x; a0[1] = (_Float16)p0.y;
            a0[2] = (_Float16)p0.z; a0[3] = (_Float16)p0.w;
            a0[4] = (_Float16)p1.x; a0[5] = (_Float16)p1.y;
            a0[6] = (_Float16)p1.z; a0[7] = (_Float16)p1.w;
            a1[0] = (_Float16)p2.x; a1[1] = (_Float16)p2.y;
            a1[2] = (_Float16)p2.z; a1[3] = (_Float16)p2.w;
            a1[4] = (_Float16)p3.x; a1[5] = (_Float16)p3.y;
            a1[6] = (_Float16)p3.z; a1[7] = (_Float16)p3.w;
        }

        // MFMA per n-tile; dump acc to the wave's LDS tile
#pragma unroll
        for (int nt = 0; nt < 4; ++nt) {
            U4H8 b0, b1;
            b0.u4 = *((const uint4*)&Bf[((0 * 4 + nt) * 64 + lane) * 4]);
            b1.u4 = *((const uint4*)&Bf[((1 * 4 + nt) * 64 + lane) * 4]);
            f32x4 acc = {0.f, 0.f, 0.f, 0.f};
            acc = __builtin_amdgcn_mfma_f32_16x16x32_f16(a0, b0.h8, acc, 0, 0, 0);
            acc = __builtin_amdgcn_mfma_f32_16x16x32_f16(a1, b1.h8, acc, 0, 0, 0);

            const int col = nt * 16 + (lane & 15);
#pragma unroll
            for (int r = 0; r < 4; ++r)
                myT[((lane >> 4) * 4 + r) * TPAD + col] = acc[r];
        }
        // DS ops are in-order per wave; wait anyway before cross-lane read
        asm volatile("s_waitcnt lgkmcnt(0)" ::: "memory");

        // coalesced epilogue: 4 passes x {float4 u-read, add, float4 store}
#pragma unroll
        for (int p = 0; p < 4; ++p) {
            const int r2    = p * 4 + (lane >> 4);
            const int ridx2 = t * 16 + r2;
            if (ridx2 < n) {
                const int brow2 = lst[ridx2];
                const float* __restrict__ urow =
                    u + (size_t)brow2 * N_LATENT + (lane & 15) * 4;
                float* __restrict__ orow =
                    out + (size_t)brow2 * N_OUT + (lane & 15) * 4;
                const float4 uq = *(const float4*)urow;
                const float4 tv = *(const float4*)(myT + r2 * TPAD + (lane & 15) * 4);
                float4 o;
                o.x = uq.x + tv.x + offv.x;
                o.y = uq.y + tv.y + offv.y;
                o.z = uq.z + tv.z + offv.z;
                o.w = uq.w + tv.w + offv.w;
                *(float4*)orow = o;
            }
        }
    }
}

extern "C" void kernel_launch(void* const* d_in, const int* in_sizes, int n_in,
                              void* d_out, int out_size, void* d_ws, size_t ws_size,
                              hipStream_t stream)
{
    const float* u       = (const float*)d_in[0];
    const int*   sid     = (const int*)d_in[1];
    const float* amat    = (const float*)d_in[2];
    const float* offsets = (const float*)d_in[3];
    float*       out     = (float*)d_out;

    const int batch    = in_sizes[0] / N_LATENT;            // 65536
    const int n_sample = in_sizes[2] / (N_LATENT * N_OUT);  // 1000

    // ws layout (ints): [0, n_sample*CSTRIDE) padded cursors
    //                   | [n_sample*CSTRIDE, +n_sample*CAP) lists
    int* cursor = (int*)d_ws;
    int* list   = cursor + (size_t)n_sample * CSTRIDE;

    hipMemsetAsync(cursor, 0, (size_t)n_sample * CSTRIDE * sizeof(int), stream);

    build_lists_kernel<<<(batch + 255) / 256, 256, 0, stream>>>(
        sid, cursor, list, batch);

    decoder_mfma_kernel<<<n_sample, 64 * NWAVES, 0, stream>>>(
        u, amat, offsets, cursor, list, out);
}